// Round 7
// baseline (431.350 us; speedup 1.0000x reference)
//
#include <hip/hip_runtime.h>
#include <stdint.h>

#define KK 5
#define SCALE_F 50000.0f
#define OC 128
#define IC 128
#define HH 56
#define WW 56
#define NB 64
#define HWSZ (HH * WW)          // 3136
#define NTAP 9
#define NWEL (OC * IC * NTAP)   // 147456
#define PW 60                   // padded row stride (u32), 240 B
#define PROWS 58                // padded rows
#define PLANE (PROWS * PW)      // 3480 u32 per (plane, n)
#define PLSTRIDE (NB * PLANE)   // 222720 u32 per plane
#define OCPB 8                  // oc per block (grid.y = 16)
#define WPT 4                   // outputs along w per thread (56 = 14 * 4)

// ---------------------------------------------------------------------------
// Kernel 1: SDP weight gen + binarize + pack.
// wpk32 layout: [wd][tap][oc] u32 -> contiguous oc => s_load_dwordx8 in bconv.
// ---------------------------------------------------------------------------
__global__ void __launch_bounds__(256) wpack_kernel(
    const float* __restrict__ M, const float* __restrict__ Z,
    const float* __restrict__ rv, uint32_t* __restrict__ wpk32) {
    int gtid = blockIdx.x * blockDim.x + threadIdx.x;
    int lane = gtid & 63;
    int wid  = gtid >> 6;            // 0..2303
    int oc   = wid / 18;
    int r    = wid - oc * 18;
    int tap  = r >> 1;
    int word = r & 1;
    int ic   = word * 64 + lane;
    int idx  = (oc * IC + ic) * NTAP + tap;

    float m  = M[idx];
    float z0 = Z[0 * NWEL + idx];
    float z1 = Z[1 * NWEL + idx];
    float z2 = Z[2 * NWEL + idx];
    float z3 = Z[3 * NWEL + idx];
    float z4 = Z[4 * NWEL + idx];
    float s  = z0 * z0 + z1 * z1 + z2 * z2 + z3 * z3 + z4 * z4;
    float A  = m * m + s * (1.0f / SCALE_F);
    float inv = 1.0f / sqrtf(A);
    float w = rv[0] * (z0 * inv);
    w += rv[1] * (z1 * inv);
    w += rv[2] * (z2 * inv);
    w += rv[3] * (z3 * inv);
    w += rv[4] * (z4 * inv);
    w += m * inv;

    unsigned long long b = __ballot(w > 0.0f);
    if (lane == 0) {
        wpk32[((word * 2 + 0) * NTAP + tap) * OC + oc] = (uint32_t)b;
        wpk32[((word * 2 + 1) * NTAP + tap) * OC + oc] = (uint32_t)(b >> 32);
    }
}

// ---------------------------------------------------------------------------
// Kernel 2: binarize + pack activations into 4 ZERO-PADDED u32 planes.
// ---------------------------------------------------------------------------
__global__ void __launch_bounds__(256) apack_kernel(
    const float* __restrict__ x, uint32_t* __restrict__ apk32) {
    int q  = blockIdx.x * blockDim.x + threadIdx.x;   // 0..200703
    int wd = blockIdx.y;                              // 0..3
    int n  = q / HWSZ;
    int hw = q - n * HWSZ;
    int h  = hw / WW;
    int w  = hw - h * WW;
    const float* xp = x + (size_t)n * IC * HWSZ + (size_t)wd * 32 * HWSZ + hw;

    uint32_t b = 0;
#pragma unroll
    for (int c = 0; c < 32; ++c)
        b |= (uint32_t)(xp[(size_t)c * HWSZ] > 0.0f) << c;

    apk32[(size_t)wd * PLSTRIDE + (size_t)n * PLANE + (size_t)(h + 1) * PW + (w + 1)] = b;
}

// ---------------------------------------------------------------------------
// Kernel 3: XNOR-popcount conv. grid = (196, 16), 256 threads.
// Per outer r-iter: ALL 8 tap VMEM loads (4 planes) issued up front, then a
// 768-inst VALU burst (1536 issue-cyc) hides VMEM/SMEM latency even at low
// occupancy. Live: cnt[32] + T[24] + addr (~70 VGPR).
// ---------------------------------------------------------------------------
__global__ void __launch_bounds__(256, 4) bconv_kernel(
    const uint32_t* __restrict__ apk32, const uint32_t* __restrict__ wpk32,
    const float* __restrict__ alpha, float* __restrict__ out) {
    __shared__ int adj[OCPB][9];               // border-class correction
    __shared__ float alf[OCPB];

    int tx  = threadIdx.x;
    int oc0 = blockIdx.y * OCPB;

    if (tx < OCPB) alf[tx] = alpha[oc0 + tx];
    if (tx < OCPB * 9) {
        int ocl = tx / 9, cls = tx % 9;
        int rc = cls / 3, cc = cls % 3;
        int nv = ((rc == 1) ? 3 : 2) * ((cc == 1) ? 3 : 2);
        int s = 0;
#pragma unroll
        for (int t = 0; t < NTAP; ++t) {
            int i = t / 3, j = t % 3;
            bool invld = (rc == 0 && i == 0) || (rc == 2 && i == 2) ||
                         (cc == 0 && j == 0) || (cc == 2 && j == 2);
            if (invld) {
#pragma unroll
                for (int wd = 0; wd < 4; ++wd)
                    s += __popc(wpk32[(wd * NTAP + t) * OC + oc0 + ocl]);
            }
        }
        adj[ocl][cls] = 128 * nv + 2 * s;
    }
    __syncthreads();

    int t  = blockIdx.x * blockDim.x + tx;     // 0..50175
    int sw = t % 14;
    int h  = (t / 14) % HH;
    int n  = t / (14 * HH);
    int w0 = sw * WPT;                         // 0,4,...,52

    const uint32_t* ap = apk32 + (size_t)n * PLANE + (size_t)h * PW + w0;

    int cnt[WPT * OCPB] = {0};                 // 32 accumulators
#pragma unroll 1
    for (int r = 0; r < 3; ++r) {
        // ---- batch-issue all 4 planes' tap loads (8 VMEM) ----
        uint32_t T[4][6];
#pragma unroll
        for (int wd = 0; wd < 4; ++wd) {
            const uint32_t* p = ap + (size_t)wd * PLSTRIDE + (size_t)r * PW;
#pragma unroll
            for (int c = 0; c < 6; ++c) T[wd][c] = p[c];
        }
        // ---- 768-instruction VALU burst over all planes ----
#pragma unroll
        for (int wd = 0; wd < 4; ++wd) {
            const uint32_t* wrow = wpk32 + (wd * NTAP + r * 3) * OC + oc0;
#pragma unroll
            for (int j = 0; j < 3; ++j) {
#pragma unroll
                for (int ocl = 0; ocl < OCPB; ++ocl) {
                    uint32_t wv = wrow[j * OC + ocl];   // uniform -> s_load x8
#pragma unroll
                    for (int o = 0; o < WPT; ++o)
                        cnt[o * OCPB + ocl] += __popc(T[wd][j + o] ^ wv);
                }
            }
        }
    }

    int rcls = (h == 0) ? 0 : ((h == HH - 1) ? 6 : 3);
    int clsL = rcls + ((w0 == 0) ? 0 : 1);
    int clsI = rcls + 1;
    int clsR = rcls + ((w0 == WW - WPT) ? 2 : 1);
    float* op = out + ((size_t)n * OC + oc0) * HWSZ + h * WW + w0;
#pragma unroll
    for (int ocl = 0; ocl < OCPB; ++ocl) {
        float a = alf[ocl];
        float4 v;
        v.x = (float)(adj[ocl][clsL] - 2 * cnt[0 * OCPB + ocl]) * a;
        v.y = (float)(adj[ocl][clsI] - 2 * cnt[1 * OCPB + ocl]) * a;
        v.z = (float)(adj[ocl][clsI] - 2 * cnt[2 * OCPB + ocl]) * a;
        v.w = (float)(adj[ocl][clsR] - 2 * cnt[3 * OCPB + ocl]) * a;
        *(float4*)(op + (size_t)ocl * HWSZ) = v;
    }
}

extern "C" void kernel_launch(void* const* d_in, const int* in_sizes, int n_in,
                              void* d_out, int out_size, void* d_ws, size_t ws_size,
                              hipStream_t stream) {
    const float* x     = (const float*)d_in[0];
    const float* M     = (const float*)d_in[1];
    const float* Z     = (const float*)d_in[2];
    const float* Alpha = (const float*)d_in[3];
    const float* rv    = (const float*)d_in[4];
    float* out = (float*)d_out;

    uint32_t* wpk32 = (uint32_t*)d_ws;                        // 18,432 B
    uint32_t* apk32 = (uint32_t*)((char*)d_ws + 32768);       // 4*222720*4 B

    // zero the padded activation planes (borders must be 0 every call)
    hipMemsetAsync(apk32, 0, (size_t)4 * PLSTRIDE * 4, stream);

    wpack_kernel<<<NWEL / 256, 256, 0, stream>>>(M, Z, rv, wpk32);
    apack_kernel<<<dim3((NB * HWSZ) / 256, 4), 256, 0, stream>>>(x, apk32);
    bconv_kernel<<<dim3((NB * HH * 14) / 256, OC / OCPB), 256, 0, stream>>>(
        apk32, wpk32, Alpha, out);
}

// Round 9
// 89.748 us; speedup vs baseline: 4.8063x; 4.8063x over previous
//
#include <hip/hip_runtime.h>
#include <stdint.h>

#define KK 5
#define SCALE_F 50000.0f
#define OC 128
#define IC 128
#define HH 56
#define WW 56
#define NB 64
#define HWSZ (HH * WW)          // 3136
#define NTAP 9
#define NWEL (OC * IC * NTAP)   // 147456

// ---- MFMA path geometry ----
#define PD 58                   // padded spatial dim
#define NICQ 8                  // 16-byte ic-chunks per pixel (128 ic)
// apk8 chunk index: ((n*PD + hh)*NICQ + icq)*PD + ww ; byte addr = chunk*16
// bfrag offset: ((kk*4 + oc_tile)*64 + lane)*16 + b   (kk = tap*4 + icb)

// ---- bitplane fallback geometry (verified R5) ----
#define PW 60
#define PROWS 58
#define PLANE (PROWS * PW)      // 3480
#define PLSTRIDE (NB * PLANE)   // 222720
#define OCPB 2
#define WPT 4

typedef int v4i  __attribute__((ext_vector_type(4)));
typedef int v16i __attribute__((ext_vector_type(16)));

// ===========================================================================
// ============================ MFMA (primary) path ==========================
// ===========================================================================

// Kernel 0: zero the padded borders of apk8 (1824 chunks per n).
__global__ void __launch_bounds__(256) border_kernel(int8_t* __restrict__ apk8) {
    int j = blockIdx.x * 256 + threadIdx.x;       // < 64*1824 = 116736
    int n  = j / 1824;
    int rj = j - n * 1824;
    int hh, icq, ww;
    if (rj < 928) {                                // rows 0 and 57
        hh = (rj / 464) * 57;
        int q = rj % 464;
        icq = q / PD;
        ww  = q - icq * PD;
    } else {                                       // cols 0 and 57, rows 1..56
        int q = rj - 928;                          // < 896
        hh = 1 + (q >> 4);
        int r2 = q & 15;
        icq = r2 >> 1;
        ww  = (r2 & 1) * 57;
    }
    size_t chunk = (((size_t)n * PD + hh) * NICQ + icq) * PD + ww;
    *(int4*)(apk8 + chunk * 16) = make_int4(0, 0, 0, 0);
}

// Kernel 1: SDP weight gen + binarize; int8 +-1 in MFMA B-fragment order.
__global__ void __launch_bounds__(256) wpack_kernel(
    const float* __restrict__ M, const float* __restrict__ Z,
    const float* __restrict__ rv, int8_t* __restrict__ bfrag) {
    int i = blockIdx.x * 256 + threadIdx.x;       // < 147456
    int oc = i / 1152;
    int r1 = i - oc * 1152;
    int ic = r1 / 9;
    int tap = r1 - ic * 9;

    float m  = M[i];
    float z0 = Z[0 * NWEL + i];
    float z1 = Z[1 * NWEL + i];
    float z2 = Z[2 * NWEL + i];
    float z3 = Z[3 * NWEL + i];
    float z4 = Z[4 * NWEL + i];
    float s  = z0 * z0 + z1 * z1 + z2 * z2 + z3 * z3 + z4 * z4;
    float A  = m * m + s * (1.0f / SCALE_F);
    float inv = 1.0f / sqrtf(A);
    float w = rv[0] * (z0 * inv);
    w += rv[1] * (z1 * inv);
    w += rv[2] * (z2 * inv);
    w += rv[3] * (z3 * inv);
    w += rv[4] * (z4 * inv);
    w += m * inv;

    int8_t sv = (w > 0.0f) ? (int8_t)1 : (int8_t)-1;
    int icb = ic >> 5, khalf = (ic >> 4) & 1, b = ic & 15;
    int kk  = tap * 4 + icb;
    int oct = oc >> 5;
    int lane = khalf * 32 + (oc & 31);
    bfrag[(size_t)((kk * 4 + oct) * 64 + lane) * 16 + b] = sv;
}

// Kernel 2: binarize f32 NCHW -> int8 chunked layout [n][hh][icq][ww][16].
__global__ void __launch_bounds__(448) apack_kernel(
    const float* __restrict__ x, int8_t* __restrict__ apk8) {
    int h = blockIdx.x;           // 0..55
    int n = blockIdx.y;           // 0..63
    int t = threadIdx.x;          // 0..447
    int w   = t % 56;
    int icq = t / 56;             // 0..7
    const float* xp = x + ((size_t)n * IC + icq * 16) * HWSZ + h * WW + w;

    uint32_t pk[4];
#pragma unroll
    for (int g = 0; g < 4; ++g) {
        uint32_t v = 0;
#pragma unroll
        for (int j = 0; j < 4; ++j) {
            float f = xp[(size_t)(g * 4 + j) * HWSZ];
            uint32_t sel = (f > 0.0f) ? 0x01u : 0xFFu;
            v |= sel << (8 * j);
        }
        pk[g] = v;
    }
    size_t chunk = (((size_t)n * PD + (h + 1)) * NICQ + icq) * PD + (w + 1);
    *(uint4*)(apk8 + chunk * 16) = make_uint4(pk[0], pk[1], pk[2], pk[3]);
}

// Kernel 3: implicit-GEMM conv via v_mfma_i32_32x32x32_i8.
__global__ void __launch_bounds__(256) bconv_kernel(
    const int8_t* __restrict__ apk8, const int8_t* __restrict__ bfrag,
    const float* __restrict__ alpha, float* __restrict__ out) {
    __shared__ float tl[4][32][33];

    int tx = threadIdx.x;
    int lane = tx & 63, wid = tx >> 6;
    int wm = wid >> 1, wn = wid & 1;
    int half = lane >> 5, l31 = lane & 31;
    int ocb = wn * 64;

    int ab[2];
    size_t ob[2];
#pragma unroll
    for (int tm = 0; tm < 2; ++tm) {
        int px = blockIdx.x * 128 + wm * 64 + tm * 32 + l31;
        int n  = px / HWSZ;
        int hw = px - n * HWSZ;
        int h  = hw / WW;
        int w  = hw - h * WW;
        ab[tm] = ((n * PD + h + 1) * NICQ + half) * PD + (w + 1);
        ob[tm] = (size_t)n * OC * HWSZ + hw + (size_t)half * HWSZ;
    }
    const int8_t* bf = bfrag + (size_t)lane * 16;

    v16i acc[2][2] = {};

#pragma unroll
    for (int kk = 0; kk < 36; ++kk) {
        int tap = kk >> 2, icb = kk & 3;
        int dh = tap / 3 - 1, dw = tap % 3 - 1;
        int off = (dh * NICQ + icb * 2) * PD + dw;

        v4i a0 = *(const v4i*)(apk8 + ((size_t)(ab[0] + off) << 4));
        v4i a1 = *(const v4i*)(apk8 + ((size_t)(ab[1] + off) << 4));
        v4i b0 = *(const v4i*)(bf + ((size_t)(kk * 4 + wn * 2 + 0) << 10));
        v4i b1 = *(const v4i*)(bf + ((size_t)(kk * 4 + wn * 2 + 1) << 10));

        acc[0][0] = __builtin_amdgcn_mfma_i32_32x32x32_i8(a0, b0, acc[0][0], 0, 0, 0);
        acc[0][1] = __builtin_amdgcn_mfma_i32_32x32x32_i8(a0, b1, acc[0][1], 0, 0, 0);
        acc[1][0] = __builtin_amdgcn_mfma_i32_32x32x32_i8(a1, b0, acc[1][0], 0, 0, 0);
        acc[1][1] = __builtin_amdgcn_mfma_i32_32x32x32_i8(a1, b1, acc[1][1], 0, 0, 0);
    }

    float (*tlw)[33] = tl[wid];
    float alf0 = alpha[ocb + l31];
    float alf1 = alpha[ocb + 32 + l31];

#pragma unroll
    for (int tm = 0; tm < 2; ++tm) {
#pragma unroll
        for (int tn = 0; tn < 2; ++tn) {
            float alf = tn ? alf1 : alf0;
            // C layout: col(oc)=lane&31, row(px)=(r&3)+8*(r>>2)+4*half
#pragma unroll
            for (int r = 0; r < 16; ++r) {
                int row = (r & 3) + 8 * (r >> 2) + 4 * half;
                tlw[row][l31] = (float)acc[tm][tn][r] * alf;
            }
            // wave-synchronous transpose read: lane -> (px=l31, oc=2r+half)
#pragma unroll
            for (int r = 0; r < 16; ++r) {
                float v = tlw[l31][2 * r + half];
                out[ob[tm] + (size_t)(ocb + tn * 32 + 2 * r) * HWSZ] = v;
            }
        }
    }
}

// ===========================================================================
// ================== bitplane fallback path (verified R5) ===================
// ===========================================================================

__global__ void __launch_bounds__(256) wpack32_kernel(
    const float* __restrict__ M, const float* __restrict__ Z,
    const float* __restrict__ rv, uint32_t* __restrict__ wpk32) {
    int gtid = blockIdx.x * blockDim.x + threadIdx.x;
    int lane = gtid & 63;
    int wid  = gtid >> 6;
    int oc   = wid / 18;
    int r    = wid - oc * 18;
    int tap  = r >> 1;
    int word = r & 1;
    int ic   = word * 64 + lane;
    int idx  = (oc * IC + ic) * NTAP + tap;

    float m  = M[idx];
    float z0 = Z[0 * NWEL + idx];
    float z1 = Z[1 * NWEL + idx];
    float z2 = Z[2 * NWEL + idx];
    float z3 = Z[3 * NWEL + idx];
    float z4 = Z[4 * NWEL + idx];
    float s  = z0 * z0 + z1 * z1 + z2 * z2 + z3 * z3 + z4 * z4;
    float A  = m * m + s * (1.0f / SCALE_F);
    float inv = 1.0f / sqrtf(A);
    float w = rv[0] * (z0 * inv);
    w += rv[1] * (z1 * inv);
    w += rv[2] * (z2 * inv);
    w += rv[3] * (z3 * inv);
    w += rv[4] * (z4 * inv);
    w += m * inv;

    unsigned long long b = __ballot(w > 0.0f);
    if (lane == 0) {
        uint64_t* wpk = (uint64_t*)wpk32;
        wpk[(oc * NTAP + tap) * 2 + word] = b;
    }
}

__global__ void __launch_bounds__(256) apack32_kernel(
    const float* __restrict__ x, uint32_t* __restrict__ apk32) {
    int q  = blockIdx.x * blockDim.x + threadIdx.x;
    int wd = blockIdx.y;
    int n  = q / HWSZ;
    int hw = q - n * HWSZ;
    int h  = hw / WW;
    int w  = hw - h * WW;
    const float* xp = x + (size_t)n * IC * HWSZ + (size_t)wd * 32 * HWSZ + hw;

    uint32_t b = 0;
#pragma unroll
    for (int c = 0; c < 32; ++c)
        b |= (uint32_t)(xp[(size_t)c * HWSZ] > 0.0f) << c;

    apk32[(size_t)wd * PLSTRIDE + (size_t)n * PLANE + (size_t)(h + 1) * PW + (w + 1)] = b;
}

__global__ void __launch_bounds__(256, 8) bconv32_kernel(
    const uint32_t* __restrict__ apk32, const uint32_t* __restrict__ wpk32,
    const float* __restrict__ alpha, float* __restrict__ out) {
    __shared__ int adj[OCPB][9];
    __shared__ float alf[OCPB];

    int tx  = threadIdx.x;
    int oc0 = blockIdx.y * OCPB;

    if (tx < OCPB) alf[tx] = alpha[oc0 + tx];
    if (tx < OCPB * 9) {
        int ocl = tx / 9, cls = tx % 9;
        int rc = cls / 3, cc = cls % 3;
        int nv = ((rc == 1) ? 3 : 2) * ((cc == 1) ? 3 : 2);
        int s = 0;
#pragma unroll
        for (int t = 0; t < NTAP; ++t) {
            int i = t / 3, j = t % 3;
            bool invld = (rc == 0 && i == 0) || (rc == 2 && i == 2) ||
                         (cc == 0 && j == 0) || (cc == 2 && j == 2);
            if (invld) {
                const uint64_t* wpk = (const uint64_t*)wpk32;
                uint64_t lo = wpk[(oc0 + ocl) * NTAP * 2 + t * 2 + 0];
                uint64_t hi = wpk[(oc0 + ocl) * NTAP * 2 + t * 2 + 1];
                s += __popcll(lo) + __popcll(hi);
            }
        }
        adj[ocl][cls] = 128 * nv + 2 * s;
    }
    __syncthreads();

    int t  = blockIdx.x * blockDim.x + tx;
    int sw = t % 14;
    int h  = (t / 14) % HH;
    int n  = t / (14 * HH);
    int w0 = sw * WPT;

    const uint32_t* ap = apk32 + (size_t)n * PLANE + (size_t)h * PW + w0;
    const uint64_t* wpk = (const uint64_t*)wpk32;

    int cnt[WPT * OCPB] = {0};
#pragma unroll 1
    for (int r = 0; r < 3; ++r) {
#pragma unroll 1
        for (int wd = 0; wd < 4; ++wd) {
            const uint32_t* p = ap + (size_t)wd * PLSTRIDE + (size_t)r * PW;
            uint32_t T[6];
#pragma unroll
            for (int c = 0; c < 6; ++c) T[c] = p[c];
#pragma unroll
            for (int j = 0; j < 3; ++j) {
#pragma unroll
                for (int ocl = 0; ocl < OCPB; ++ocl) {
                    uint64_t w2 = wpk[(oc0 + ocl) * NTAP * 2 + (r * 3 + j) * 2 + (wd >> 1)];
                    uint32_t wv = (wd & 1) ? (uint32_t)(w2 >> 32) : (uint32_t)w2;
#pragma unroll
                    for (int o = 0; o < WPT; ++o)
                        cnt[o * OCPB + ocl] += __popc(T[j + o] ^ wv);
                }
            }
        }
    }

    int rcls = (h == 0) ? 0 : ((h == HH - 1) ? 6 : 3);
    int clsL = rcls + ((w0 == 0) ? 0 : 1);
    int clsI = rcls + 1;
    int clsR = rcls + ((w0 == WW - WPT) ? 2 : 1);
    float* op = out + ((size_t)n * OC + oc0) * HWSZ + h * WW + w0;
#pragma unroll
    for (int ocl = 0; ocl < OCPB; ++ocl) {
        float a = alf[ocl];
        float4 v;
        v.x = (float)(adj[ocl][clsL] - 2 * cnt[0 * OCPB + ocl]) * a;
        v.y = (float)(adj[ocl][clsI] - 2 * cnt[1 * OCPB + ocl]) * a;
        v.z = (float)(adj[ocl][clsI] - 2 * cnt[2 * OCPB + ocl]) * a;
        v.w = (float)(adj[ocl][clsR] - 2 * cnt[3 * OCPB + ocl]) * a;
        *(float4*)(op + (size_t)ocl * HWSZ) = v;
    }
}

extern "C" void kernel_launch(void* const* d_in, const int* in_sizes, int n_in,
                              void* d_out, int out_size, void* d_ws, size_t ws_size,
                              hipStream_t stream) {
    const float* x     = (const float*)d_in[0];
    const float* M     = (const float*)d_in[1];
    const float* Z     = (const float*)d_in[2];
    const float* Alpha = (const float*)d_in[3];
    const float* rv    = (const float*)d_in[4];
    float* out = (float*)d_out;

    const size_t mfma_needed = 196608 + (size_t)NB * PD * NICQ * PD * 16;  // ~27.8 MB

    if (ws_size >= mfma_needed) {
        int8_t* bfrag = (int8_t*)d_ws;                      // 147,456 B
        int8_t* apk8  = (int8_t*)d_ws + 196608;             // 27,557,888 B

        border_kernel<<<(NB * 1824) / 256, 256, 0, stream>>>(apk8);
        wpack_kernel<<<NWEL / 256, 256, 0, stream>>>(M, Z, rv, bfrag);
        apack_kernel<<<dim3(HH, NB), 448, 0, stream>>>(x, apk8);
        bconv_kernel<<<(NB * HWSZ) / 128, 256, 0, stream>>>(apk8, bfrag, Alpha, out);
    } else {
        // verified bitplane fallback (R5): wpk as u64 pairs, 4 u32 planes
        uint32_t* wpk32 = (uint32_t*)d_ws;                  // 18,432 B
        uint32_t* apk32 = (uint32_t*)((char*)d_ws + 32768); // 3,563,520 B

        hipMemsetAsync(apk32, 0, (size_t)4 * PLSTRIDE * 4, stream);
        wpack32_kernel<<<NWEL / 256, 256, 0, stream>>>(M, Z, rv, wpk32);
        apack32_kernel<<<dim3((NB * HWSZ) / 256, 4), 256, 0, stream>>>(x, apk32);
        bconv32_kernel<<<dim3((NB * HH * 14) / 256, OC / OCPB), 256, 0, stream>>>(
            apk32, wpk32, Alpha, out);
    }
}